// Round 23
// baseline (64.271 us; speedup 1.0000x reference)
//
#include <hip/hip_runtime.h>

#define AS1 __attribute__((address_space(1)))
#define AS3 __attribute__((address_space(3)))
#define CHUNK 256
#define NB 256
#define PIGRID 2048   // R22: grid 1024 capped fused_k at 16 waves/CU (37% occ,
                      // 39us). 2048 -> 8 blocks/CU, full 32-wave residency.

typedef unsigned int uint;
typedef unsigned short ushort;
typedef __attribute__((ext_vector_type(4))) float f32x4;
typedef __attribute__((ext_vector_type(8))) _Float16 h8;
typedef __attribute__((ext_vector_type(2))) __fp16 fp16x2;

union H8 { uint u[4]; h8 h; };

__device__ __forceinline__ void gld_lds16(const float* g, float* l) {
  __builtin_amdgcn_global_load_lds((const AS1 void*)g, (AS3 void*)l, 16, 0, 0);
}
__device__ __forceinline__ uint pkrtz(float a, float b) {
  union { fp16x2 h; uint u; } c;
  c.h = __builtin_amdgcn_cvt_pkrtz(a, b);
  return c.u;
}

#define WAITVM0  do { asm volatile("s_waitcnt vmcnt(0)" ::: "memory"); __builtin_amdgcn_sched_barrier(0); } while (0)
#define WAITLGKM do { asm volatile("s_waitcnt lgkmcnt(0)" ::: "memory"); __builtin_amdgcn_sched_barrier(0); } while (0)
#define BAR __builtin_amdgcn_s_barrier()

// Fused prep+pi: streams r (argmax via 8-lane cooperative shfl reduce) and ri
// (pi column sums + selected wpair) in ONE pass. 8 PIDO slots fully unrolled:
// ppb(245) < stride(256) so each thread runs exactly one pass with all 16
// loads in flight before the shfl chains retire (max MLP).
__global__ __launch_bounds__(256) void fused_k(
    const float* __restrict__ r, const float* __restrict__ ri,
    unsigned char* __restrict__ zb, float* __restrict__ wpairf,
    float* __restrict__ pigp, int n)
{
  __shared__ float4 s[256];
  const int t = threadIdx.x;
  const int cg = t & 7;
  const int pr = t >> 3;
  const int ppb = (n + PIGRID - 1) / PIGRID;
  const int p0 = blockIdx.x * ppb;
  const int p1 = min(p0 + ppb, n);

  float4 acc0 = make_float4(0,0,0,0), acc1 = make_float4(0,0,0,0),
         acc2 = make_float4(0,0,0,0), acc3 = make_float4(0,0,0,0),
         acc4 = make_float4(0,0,0,0), acc5 = make_float4(0,0,0,0),
         acc6 = make_float4(0,0,0,0), acc7 = make_float4(0,0,0,0);
  const float4* rif = (const float4*)ri;

#define PIDO(PX, ACC) { \
    float2 rv = *(const float2*)(r + (size_t)(PX) * 16 + cg * 2); \
    float4 v = rif[(size_t)(PX) * 8 + cg]; \
    float bv = rv.x; int bi = cg * 2; \
    if (rv.y > bv) { bv = rv.y; bi = cg * 2 + 1; } \
    _Pragma("unroll") for (int m_ = 1; m_ <= 4; m_ <<= 1) { \
      float ov = __shfl_xor(bv, m_, 64); \
      int oi = __shfl_xor(bi, m_, 64); \
      if (ov > bv || (ov == bv && oi < bi)) { bv = ov; bi = oi; } \
    } \
    if (cg == (bi >> 1)) { \
      float2 wp = (bi & 1) ? make_float2(v.z, v.w) : make_float2(v.x, v.y); \
      *(float2*)&wpairf[(size_t)(PX) * 2] = wp; \
    } \
    if (cg == 0) zb[PX] = (unsigned char)bi; \
    ACC.x += v.x; ACC.y += v.y; ACC.z += v.z; ACC.w += v.w; }

  for (int p = p0 + pr; p < p1; p += 256) {
    int pa = p,        pb = p + 32,  pc = p + 64,  pd = p + 96;
    int pe = p + 128,  pf = p + 160, pg = p + 192, ph = p + 224;
    if (pa < p1) PIDO(pa, acc0)
    if (pb < p1) PIDO(pb, acc1)
    if (pc < p1) PIDO(pc, acc2)
    if (pd < p1) PIDO(pd, acc3)
    if (pe < p1) PIDO(pe, acc4)
    if (pf < p1) PIDO(pf, acc5)
    if (pg < p1) PIDO(pg, acc6)
    if (ph < p1) PIDO(ph, acc7)
  }
#undef PIDO
  acc0.x += acc1.x + acc2.x + acc3.x + acc4.x + acc5.x + acc6.x + acc7.x;
  acc0.y += acc1.y + acc2.y + acc3.y + acc4.y + acc5.y + acc6.y + acc7.y;
  acc0.z += acc1.z + acc2.z + acc3.z + acc4.z + acc5.z + acc6.z + acc7.z;
  acc0.w += acc1.w + acc2.w + acc3.w + acc4.w + acc5.w + acc6.w + acc7.w;
  s[t] = acc0;
  __syncthreads();
  if (t < 8) {
    float4 a = s[t];
#pragma unroll
    for (int q = 1; q < 32; ++q) {
      float4 v = s[t + q * 8];
      a.x += v.x; a.y += v.y; a.z += v.z; a.w += v.w;
    }
    *(float4*)&pigp[blockIdx.x * 32 + t * 4] = a;
  }
}

// Gram-MFMA cluster accumulation (R18 proven).
#define CLUSTER_MFMA(CIDX, T00a,T01a,T11a,T20a,T21a, T00b,T01b,T11b,T20b,T21b) { \
  const int c_ = (CIDX); \
  int cnt_ = lcnt[b][c_]; if (cnt_ > 64) cnt_ = 64; \
  const int ng_ = (cnt_ + 31) >> 5; \
  for (int g_ = 0; g_ < ng_; ++g_) { \
    alignas(16) ushort praw_[8]; \
    *(uint4*)praw_ = *(const uint4*)&list[b][c_][(g_ << 5) + ((l >> 4) << 3)]; \
    const int sbase_ = (g_ << 5) + ((l >> 4) << 3); \
    int p_[8]; \
    _Pragma("unroll") for (int j = 0; j < 8; ++j) \
      p_[j] = (sbase_ + j < cnt_) ? (int)praw_[j] : 256; \
    uint W_[8]; \
    _Pragma("unroll") for (int j = 0; j < 8; ++j) W_[j] = wls[b][p_[j]]; \
    H8 F0_, F1_, ws0_, ws1_; \
    _Pragma("unroll") for (int j = 0; j < 4; ++j) { \
      uint l0 = xh[b][p_[2*j]*34 + c16], l1 = xh[b][p_[2*j+1]*34 + c16]; \
      uint h0 = xh[b][p_[2*j]*34 + 16 + c16], h1 = xh[b][p_[2*j+1]*34 + 16 + c16]; \
      F0_.u[j] = l0 | (l1 << 16); \
      F1_.u[j] = h0 | (h1 << 16); \
      ws0_.u[j] = (W_[2*j] & 0xffffu) | (W_[2*j+1] << 16); \
      ws1_.u[j] = (W_[2*j] >> 16) | (W_[2*j+1] & 0xffff0000u); \
    } \
    H8 s00_, s01_, s10_, s11_, i20_, i21_; \
    s00_.h = F0_.h * ws0_.h; s01_.h = F1_.h * ws0_.h; \
    s10_.h = F0_.h * ws1_.h; s11_.h = F1_.h * ws1_.h; \
    _Pragma("unroll") for (int j = 0; j < 4; ++j) { \
      i20_.u[j] = lane16 ? ws0_.u[j] : 0u; \
      i21_.u[j] = lane16 ? ws1_.u[j] : 0u; \
    } \
    T00a = __builtin_amdgcn_mfma_f32_16x16x32_f16(s00_.h, s00_.h, T00a, 0,0,0); \
    T01a = __builtin_amdgcn_mfma_f32_16x16x32_f16(s00_.h, s01_.h, T01a, 0,0,0); \
    T11a = __builtin_amdgcn_mfma_f32_16x16x32_f16(s01_.h, s01_.h, T11a, 0,0,0); \
    T20a = __builtin_amdgcn_mfma_f32_16x16x32_f16(i20_.h, s00_.h, T20a, 0,0,0); \
    T21a = __builtin_amdgcn_mfma_f32_16x16x32_f16(i20_.h, s01_.h, T21a, 0,0,0); \
    T00b = __builtin_amdgcn_mfma_f32_16x16x32_f16(s10_.h, s10_.h, T00b, 0,0,0); \
    T01b = __builtin_amdgcn_mfma_f32_16x16x32_f16(s10_.h, s11_.h, T01b, 0,0,0); \
    T11b = __builtin_amdgcn_mfma_f32_16x16x32_f16(s11_.h, s11_.h, T11b, 0,0,0); \
    T20b = __builtin_amdgcn_mfma_f32_16x16x32_f16(i21_.h, s10_.h, T20b, 0,0,0); \
    T21b = __builtin_amdgcn_mfma_f32_16x16x32_f16(i21_.h, s11_.h, T21b, 0,0,0); \
  } }

// 3KB/comp partials exploiting gram symmetry (verified R19-R22):
// sec0 = Q00 (sym), sec1 = Q11 (sym), sec2 = Q01^T.
#define STORE_MFMA(COMP, T00,T01,T11,T20,T21) { \
  float* dst_ = m2p + ((size_t)blockIdx.x * 32 + (COMP)) * 768; \
  const int r0_ = (l >> 4) << 2; \
  f32x4 t00_ = T00, t01_ = T01, t11_ = T11; \
  *(float4*)&dst_[c16 * 16 + r0_] = *(float4*)&t00_; \
  *(float4*)&dst_[256 + c16 * 16 + r0_] = *(float4*)&t11_; \
  *(float4*)&dst_[512 + c16 * 16 + r0_] = *(float4*)&t01_; \
  if (l < 16) { \
    musp[((size_t)blockIdx.x * 32 + (COMP)) * 32 + l] = T20[0]; \
    musp[((size_t)blockIdx.x * 32 + (COMP)) * 32 + 16 + l] = T21[0]; \
  } }

__global__ __launch_bounds__(512, 2) void mstep_k(
    const float* __restrict__ X, const unsigned char* __restrict__ zb,
    const float* __restrict__ wpairf,
    float* __restrict__ m2p, float* __restrict__ musp, float* __restrict__ dnp,
    int n, int nchunks)
{
  __shared__ float xf32[CHUNK * 32];                 // 32KB gld_lds landing
  __shared__ __align__(16) ushort xh[2][257 * 34];   // fp16 pt-major, row 256 = 0
  __shared__ uint wls[2][257];
  __shared__ __align__(16) ushort list[2][16][64];
  __shared__ int lcnt[2][16];
  __shared__ float dn[16][2];

  const int t = threadIdx.x;
  const int wv = t >> 6;
  const int l = t & 63;
  const int c16 = l & 15;
  const bool lane16 = (l & 15) == 0;
  const int G = gridDim.x;

  f32x4 z4 = {0.f, 0.f, 0.f, 0.f};
  f32x4 a0_00=z4, a0_01=z4, a0_11=z4, a0_20=z4, a0_21=z4;
  f32x4 b0_00=z4, b0_01=z4, b0_11=z4, b0_20=z4, b0_21=z4;
  f32x4 a1_00=z4, a1_01=z4, a1_11=z4, a1_20=z4, a1_21=z4;
  f32x4 b1_00=z4, b1_01=z4, b1_11=z4, b1_20=z4, b1_21=z4;

  float wr0 = 0.f, wr1 = 0.f; int zr = 0;

  auto STAGEX = [&](int ch) {
#pragma unroll
    for (int q = 0; q < 4; ++q) {
      int gi = ch * CHUNK + wv * 32 + q * 8 + (l >> 3);
      if (gi > n - 1) gi = n - 1;
      gld_lds16(X + (size_t)gi * 32 + ((l & 7) << 2), &xf32[(wv * 32 + q * 8) * 32]);
    }
  };
  auto LOADWZ = [&](int ch) {
    if (t < CHUNK) {
      int gi = ch * CHUNK + t;
      if (gi < n) {
        float2 w2 = *(const float2*)(wpairf + (size_t)gi * 2);
        wr0 = w2.x; wr1 = w2.y; zr = zb[gi];
      } else { wr0 = 0.f; wr1 = 0.f; zr = 0; }
    }
  };
  auto CVT = [&](int nb) {
    const int p = t >> 1, hh = t & 1;
    const float4* s4 = (const float4*)(xf32 + p * 32 + hh * 16);
    uint* dst = (uint*)&xh[nb][p * 34 + hh * 16];
#pragma unroll
    for (int i = 0; i < 4; ++i) {
      int ii = (i + p) & 3;
      float4 v = s4[ii];
      dst[2 * ii]     = pkrtz(v.x, v.y);
      dst[2 * ii + 1] = pkrtz(v.z, v.w);
    }
    if (t < CHUNK) {
      wls[nb][t] = pkrtz(sqrtf(wr0), sqrtf(wr1));
      atomicAdd(&dn[zr][0], wr0);
      atomicAdd(&dn[zr][1], wr1);
      int pos = atomicAdd(&lcnt[nb][zr], 1);
      if (pos < 64) list[nb][zr][pos] = (ushort)t;
    }
  };

  if (t < 32) ((int*)lcnt)[t] = 0;
  if (t < 32) ((float*)dn)[t] = 0.f;
  if (t < 17) {
    ((uint*)&xh[0][256 * 34])[t] = 0;
    ((uint*)&xh[1][256 * 34])[t] = 0;
  }
  if (t == 0) { wls[0][256] = 0; wls[1][256] = 0; }

  int ch = blockIdx.x;
  int b = 0;
  if (ch < nchunks) {
    STAGEX(ch); LOADWZ(ch);
    WAITVM0; WAITLGKM; BAR;
    CVT(0);
    WAITLGKM; BAR;
    if (ch + G < nchunks) { STAGEX(ch + G); LOADWZ(ch + G); }
    while (true) {
      CLUSTER_MFMA(wv * 2 + 0, a0_00,a0_01,a0_11,a0_20,a0_21,
                               b0_00,b0_01,b0_11,b0_20,b0_21)
      CLUSTER_MFMA(wv * 2 + 1, a1_00,a1_01,a1_11,a1_20,a1_21,
                               b1_00,b1_01,b1_11,b1_20,b1_21)
      int chn = ch + G;
      if (chn >= nchunks) break;
      WAITVM0; WAITLGKM; BAR;
      if (t < 16) lcnt[b][t] = 0;
      CVT(b ^ 1);
      WAITLGKM; BAR;
      if (chn + G < nchunks) { STAGEX(chn + G); LOADWZ(chn + G); }
      b ^= 1; ch = chn;
    }
  }

  STORE_MFMA((wv * 2 + 0) * 2 + 0, a0_00,a0_01,a0_11,a0_20,a0_21)
  STORE_MFMA((wv * 2 + 0) * 2 + 1, b0_00,b0_01,b0_11,b0_20,b0_21)
  STORE_MFMA((wv * 2 + 1) * 2 + 0, a1_00,a1_01,a1_11,a1_20,a1_21)
  STORE_MFMA((wv * 2 + 1) * 2 + 1, b1_00,b1_01,b1_11,b1_20,b1_21)
  if (t < 32) dnp[blockIdx.x * 32 + t] = dn[t >> 1][t & 1];
}

// Partial-reduction: m2p [NB][24576] via 192 blocks, musp via 8, dnp via 1,
// pigp [PIGRID][32] via 8 slice-blocks (PIGRID/8 rows each -> pigr8[8][32]).
__global__ __launch_bounds__(256) void reduce_k(
    const float* __restrict__ m2p, const float* __restrict__ musp,
    const float* __restrict__ dnp, const float* __restrict__ pigp,
    float* __restrict__ m2r, float* __restrict__ musr,
    float* __restrict__ dnr, float* __restrict__ pigr8, int nb)
{
  const int t = threadIdx.x;
  const int bid = blockIdx.x;

  if (bid < 200) {
    __shared__ float4 red[256];
    const float* in; float* outp; int rs, colbase;
    if (bid < 192) { in = m2p;  outp = m2r;  rs = 24576; colbase = bid * 32; }
    else           { in = musp; outp = musr; rs = 1024;  colbase = (bid - 192) * 32; }
    const int col = colbase + (t & 31);
    float4 a = make_float4(0.f, 0.f, 0.f, 0.f);
#pragma unroll 4
    for (int bb = t >> 5; bb < nb; bb += 8) {
      float4 v = *(const float4*)&in[(size_t)bb * rs + col * 4];
      a.x += v.x; a.y += v.y; a.z += v.z; a.w += v.w;
    }
    red[t] = a;
    __syncthreads();
    if (t < 32) {
      float4 s = red[t];
#pragma unroll
      for (int q = 1; q < 8; ++q) {
        float4 v = red[t + q * 32];
        s.x += v.x; s.y += v.y; s.z += v.z; s.w += v.w;
      }
      *(float4*)&outp[col * 4] = s;
    }
  } else {
    __shared__ float redf[256];
    const float* in; float* outp; int rows, row0;
    if (bid == 200) { in = dnp; outp = dnr; rows = nb; row0 = 0; }
    else {
      in = pigp; outp = pigr8 + (bid - 201) * 32;
      rows = PIGRID / 8; row0 = (bid - 201) * (PIGRID / 8);
    }
    float a = 0.f;
    const int c = t & 31;
#pragma unroll 4
    for (int bb = t >> 5; bb < rows; bb += 8) a += in[(row0 + bb) * 32 + c];
    redf[t] = a;
    __syncthreads();
    if (t < 32) {
      float s = redf[t];
#pragma unroll
      for (int q = 1; q < 8; ++q) s += redf[t + q * 32];
      outp[c] = s;
    }
  }
}

// Epilogue: reconstruct full 32x32 covs from the 3-section symmetric layout.
__global__ __launch_bounds__(256) void finalize_k(
    const float* __restrict__ pigr8, const float* __restrict__ dnr,
    const float* __restrict__ musr, const float* __restrict__ m2r,
    float* __restrict__ out, int n)
{
  const int c = blockIdx.x;
  const int t = threadIdx.x;
  __shared__ float mu[32];
  float safe = fmaxf(dnr[c], 1e-10f);
  if (t < 32) {
    float m = musr[c * 32 + t] / safe;
    mu[t] = m;
    out[32 + c * 32 + t] = m;                        // mus
  }
  if (c == 0 && t < 32) {
    float p = 0.f;
#pragma unroll
    for (int s = 0; s < 8; ++s) p += pigr8[s * 32 + t];
    out[t] = p / (float)n;                           // pi
  }
  __syncthreads();
  const int d1 = t >> 3;
  const int c0 = (t * 4) & 31;
  const float* base = m2r + c * 768;
  float vals[4];
  if (d1 < 16) {
    if (c0 < 16) {
      float4 v = *(const float4*)&base[d1 * 16 + c0];
      vals[0]=v.x; vals[1]=v.y; vals[2]=v.z; vals[3]=v.w;
    } else {
      int cc = c0 - 16;
#pragma unroll
      for (int j = 0; j < 4; ++j) vals[j] = base[512 + (cc + j) * 16 + d1];
    }
  } else {
    int dd = d1 - 16;
    if (c0 < 16) {
      float4 v = *(const float4*)&base[512 + dd * 16 + c0];
      vals[0]=v.x; vals[1]=v.y; vals[2]=v.z; vals[3]=v.w;
    } else {
      float4 v = *(const float4*)&base[256 + dd * 16 + (c0 - 16)];
      vals[0]=v.x; vals[1]=v.y; vals[2]=v.z; vals[3]=v.w;
    }
  }
  float mud1 = mu[d1];
  float4 cov;
  cov.x = vals[0] / safe - mud1 * mu[c0 + 0];
  cov.y = vals[1] / safe - mud1 * mu[c0 + 1];
  cov.z = vals[2] / safe - mud1 * mu[c0 + 2];
  cov.w = vals[3] / safe - mud1 * mu[c0 + 3];
  *(float4*)&out[32 + 1024 + c * 1024 + t * 4] = cov;  // covs
}

extern "C" void kernel_launch(void* const* d_in, const int* in_sizes, int n_in,
                              void* d_out, int out_size, void* d_ws, size_t ws_size,
                              hipStream_t stream) {
  const float* X  = (const float*)d_in[0];
  const float* r  = (const float*)d_in[1];
  const float* ri = (const float*)d_in[2];
  float* out = (float*)d_out;
  const int n = in_sizes[0] / 32;
  const int nchunks = (n + CHUNK - 1) / CHUNK;

  // ws layout: [m2p | musp | dnp | m2r | musr | dnr | pigr8 | pigp | wpair | zbuf]
  float* m2p   = (float*)d_ws;                          // NB*32*768
  float* musp  = m2p + (size_t)NB * 32 * 768;           // NB*32*32
  float* dnp   = musp + (size_t)NB * 32 * 32;           // NB*32
  float* m2r   = dnp + (size_t)NB * 32;                 // 24576
  float* musr  = m2r + 24576;                           // 1024
  float* dnr   = musr + 1024;                           // 32
  float* pigr8 = dnr + 32;                              // 8*32
  float* pigp  = pigr8 + 8 * 32;                        // PIGRID*32
  float* wpair = pigp + (size_t)PIGRID * 32;            // 2n
  unsigned char* zbuf = (unsigned char*)(wpair + 2 * (size_t)n);  // n + pad

  fused_k<<<PIGRID, 256, 0, stream>>>(r, ri, zbuf, wpair, pigp, n);
  mstep_k<<<NB, 512, 0, stream>>>(X, zbuf, wpair, m2p, musp, dnp, n, nchunks);
  reduce_k<<<209, 256, 0, stream>>>(m2p, musp, dnp, pigp, m2r, musr, dnr, pigr8, NB);
  finalize_k<<<32, 256, 0, stream>>>(pigr8, dnr, musr, m2r, out, n);
}

// Round 24
// 59.774 us; speedup vs baseline: 1.0752x; 1.0752x over previous
//
#include <hip/hip_runtime.h>

#define AS1 __attribute__((address_space(1)))
#define AS3 __attribute__((address_space(3)))
#define CHUNK 256
#define NB 256
#define PIGRID 2048

typedef unsigned int uint;
typedef unsigned short ushort;
typedef __attribute__((ext_vector_type(4))) float f32x4;
typedef __attribute__((ext_vector_type(8))) _Float16 h8;
typedef __attribute__((ext_vector_type(2))) __fp16 fp16x2;

union H8 { uint u[4]; h8 h; };

__device__ __forceinline__ void gld_lds16(const float* g, float* l) {
  __builtin_amdgcn_global_load_lds((const AS1 void*)g, (AS3 void*)l, 16, 0, 0);
}
__device__ __forceinline__ uint pkrtz(float a, float b) {
  union { fp16x2 h; uint u; } c;
  c.h = __builtin_amdgcn_cvt_pkrtz(a, b);
  return c.u;
}

#define WAITVM0  do { asm volatile("s_waitcnt vmcnt(0)" ::: "memory"); __builtin_amdgcn_sched_barrier(0); } while (0)
#define WAITLGKM do { asm volatile("s_waitcnt lgkmcnt(0)" ::: "memory"); __builtin_amdgcn_sched_barrier(0); } while (0)
#define BAR __builtin_amdgcn_s_barrier()

// Fused prep+pi, two-phase (R23: per-point 6-shfl chain was the wall).
// Phase 1: one thread per point, serial 16-way argmax (4 independent float4
// loads, max MLP, zero cross-lane) -> z to LDS + zb.
// Phase 2: cooperative ri stream; z read from LDS (1B), owner writes wpair.
__global__ __launch_bounds__(256) void fused_k(
    const float* __restrict__ r, const float* __restrict__ ri,
    unsigned char* __restrict__ zb, float* __restrict__ wpairf,
    float* __restrict__ pigp, int n)
{
  __shared__ unsigned char zs[256];
  __shared__ float4 s[256];
  const int t = threadIdx.x;
  const int cg = t & 7;
  const int pr = t >> 3;
  const int ppb = (n + PIGRID - 1) / PIGRID;   // 245 for n=500k
  const int p0 = blockIdx.x * ppb;
  const int p1 = min(p0 + ppb, n);

  // ---- phase 1: per-thread argmax ----
  int myp = p0 + t;
  if (t < ppb && myp < n) {
    const float4* rr = (const float4*)(r + (size_t)myp * 16);
    float4 a0 = rr[0], a1 = rr[1], a2 = rr[2], a3 = rr[3];
    float best = a0.x; int z = 0;
#define CHK(v, c) if ((v) > best) { best = (v); z = (c); }
    CHK(a0.y,1) CHK(a0.z,2) CHK(a0.w,3)
    CHK(a1.x,4) CHK(a1.y,5) CHK(a1.z,6) CHK(a1.w,7)
    CHK(a2.x,8) CHK(a2.y,9) CHK(a2.z,10) CHK(a2.w,11)
    CHK(a3.x,12) CHK(a3.y,13) CHK(a3.z,14) CHK(a3.w,15)
#undef CHK
    zs[t] = (unsigned char)z;
    zb[myp] = (unsigned char)z;
  }
  __syncthreads();

  // ---- phase 2: cooperative ri stream ----
  float4 acc0 = make_float4(0,0,0,0), acc1 = make_float4(0,0,0,0),
         acc2 = make_float4(0,0,0,0), acc3 = make_float4(0,0,0,0),
         acc4 = make_float4(0,0,0,0), acc5 = make_float4(0,0,0,0),
         acc6 = make_float4(0,0,0,0), acc7 = make_float4(0,0,0,0);
  const float4* rif = (const float4*)ri;

#define PIDO(PX, ACC) { \
    float4 v = rif[(size_t)(PX) * 8 + cg]; \
    int zv = zs[(PX) - p0]; \
    if (cg == (zv >> 1)) { \
      float2 wp = (zv & 1) ? make_float2(v.z, v.w) : make_float2(v.x, v.y); \
      *(float2*)&wpairf[(size_t)(PX) * 2] = wp; \
    } \
    ACC.x += v.x; ACC.y += v.y; ACC.z += v.z; ACC.w += v.w; }

  {
    int p = p0 + pr;
    int pa = p,        pb = p + 32,  pc = p + 64,  pd = p + 96;
    int pe = p + 128,  pf = p + 160, pg = p + 192, ph = p + 224;
    if (pa < p1) PIDO(pa, acc0)
    if (pb < p1) PIDO(pb, acc1)
    if (pc < p1) PIDO(pc, acc2)
    if (pd < p1) PIDO(pd, acc3)
    if (pe < p1) PIDO(pe, acc4)
    if (pf < p1) PIDO(pf, acc5)
    if (pg < p1) PIDO(pg, acc6)
    if (ph < p1) PIDO(ph, acc7)
  }
#undef PIDO
  acc0.x += acc1.x + acc2.x + acc3.x + acc4.x + acc5.x + acc6.x + acc7.x;
  acc0.y += acc1.y + acc2.y + acc3.y + acc4.y + acc5.y + acc6.y + acc7.y;
  acc0.z += acc1.z + acc2.z + acc3.z + acc4.z + acc5.z + acc6.z + acc7.z;
  acc0.w += acc1.w + acc2.w + acc3.w + acc4.w + acc5.w + acc6.w + acc7.w;
  s[t] = acc0;
  __syncthreads();
  if (t < 8) {
    float4 a = s[t];
#pragma unroll
    for (int q = 1; q < 32; ++q) {
      float4 v = s[t + q * 8];
      a.x += v.x; a.y += v.y; a.z += v.z; a.w += v.w;
    }
    *(float4*)&pigp[blockIdx.x * 32 + t * 4] = a;
  }
}

// Gram-MFMA cluster accumulation (R18 proven).
#define CLUSTER_MFMA(CIDX, T00a,T01a,T11a,T20a,T21a, T00b,T01b,T11b,T20b,T21b) { \
  const int c_ = (CIDX); \
  int cnt_ = lcnt[b][c_]; if (cnt_ > 64) cnt_ = 64; \
  const int ng_ = (cnt_ + 31) >> 5; \
  for (int g_ = 0; g_ < ng_; ++g_) { \
    alignas(16) ushort praw_[8]; \
    *(uint4*)praw_ = *(const uint4*)&list[b][c_][(g_ << 5) + ((l >> 4) << 3)]; \
    const int sbase_ = (g_ << 5) + ((l >> 4) << 3); \
    int p_[8]; \
    _Pragma("unroll") for (int j = 0; j < 8; ++j) \
      p_[j] = (sbase_ + j < cnt_) ? (int)praw_[j] : 256; \
    uint W_[8]; \
    _Pragma("unroll") for (int j = 0; j < 8; ++j) W_[j] = wls[b][p_[j]]; \
    H8 F0_, F1_, ws0_, ws1_; \
    _Pragma("unroll") for (int j = 0; j < 4; ++j) { \
      uint l0 = xh[b][p_[2*j]*34 + c16], l1 = xh[b][p_[2*j+1]*34 + c16]; \
      uint h0 = xh[b][p_[2*j]*34 + 16 + c16], h1 = xh[b][p_[2*j+1]*34 + 16 + c16]; \
      F0_.u[j] = l0 | (l1 << 16); \
      F1_.u[j] = h0 | (h1 << 16); \
      ws0_.u[j] = (W_[2*j] & 0xffffu) | (W_[2*j+1] << 16); \
      ws1_.u[j] = (W_[2*j] >> 16) | (W_[2*j+1] & 0xffff0000u); \
    } \
    H8 s00_, s01_, s10_, s11_, i20_, i21_; \
    s00_.h = F0_.h * ws0_.h; s01_.h = F1_.h * ws0_.h; \
    s10_.h = F0_.h * ws1_.h; s11_.h = F1_.h * ws1_.h; \
    _Pragma("unroll") for (int j = 0; j < 4; ++j) { \
      i20_.u[j] = lane16 ? ws0_.u[j] : 0u; \
      i21_.u[j] = lane16 ? ws1_.u[j] : 0u; \
    } \
    T00a = __builtin_amdgcn_mfma_f32_16x16x32_f16(s00_.h, s00_.h, T00a, 0,0,0); \
    T01a = __builtin_amdgcn_mfma_f32_16x16x32_f16(s00_.h, s01_.h, T01a, 0,0,0); \
    T11a = __builtin_amdgcn_mfma_f32_16x16x32_f16(s01_.h, s01_.h, T11a, 0,0,0); \
    T20a = __builtin_amdgcn_mfma_f32_16x16x32_f16(i20_.h, s00_.h, T20a, 0,0,0); \
    T21a = __builtin_amdgcn_mfma_f32_16x16x32_f16(i20_.h, s01_.h, T21a, 0,0,0); \
    T00b = __builtin_amdgcn_mfma_f32_16x16x32_f16(s10_.h, s10_.h, T00b, 0,0,0); \
    T01b = __builtin_amdgcn_mfma_f32_16x16x32_f16(s10_.h, s11_.h, T01b, 0,0,0); \
    T11b = __builtin_amdgcn_mfma_f32_16x16x32_f16(s11_.h, s11_.h, T11b, 0,0,0); \
    T20b = __builtin_amdgcn_mfma_f32_16x16x32_f16(i21_.h, s10_.h, T20b, 0,0,0); \
    T21b = __builtin_amdgcn_mfma_f32_16x16x32_f16(i21_.h, s11_.h, T21b, 0,0,0); \
  } }

// 3KB/comp partials exploiting gram symmetry (verified R19-R23):
// sec0 = Q00 (sym), sec1 = Q11 (sym), sec2 = Q01^T.
#define STORE_MFMA(COMP, T00,T01,T11,T20,T21) { \
  float* dst_ = m2p + ((size_t)blockIdx.x * 32 + (COMP)) * 768; \
  const int r0_ = (l >> 4) << 2; \
  f32x4 t00_ = T00, t01_ = T01, t11_ = T11; \
  *(float4*)&dst_[c16 * 16 + r0_] = *(float4*)&t00_; \
  *(float4*)&dst_[256 + c16 * 16 + r0_] = *(float4*)&t11_; \
  *(float4*)&dst_[512 + c16 * 16 + r0_] = *(float4*)&t01_; \
  if (l < 16) { \
    musp[((size_t)blockIdx.x * 32 + (COMP)) * 32 + l] = T20[0]; \
    musp[((size_t)blockIdx.x * 32 + (COMP)) * 32 + 16 + l] = T21[0]; \
  } }

__global__ __launch_bounds__(512, 2) void mstep_k(
    const float* __restrict__ X, const unsigned char* __restrict__ zb,
    const float* __restrict__ wpairf,
    float* __restrict__ m2p, float* __restrict__ musp, float* __restrict__ dnp,
    int n, int nchunks)
{
  __shared__ float xf32[CHUNK * 32];                 // 32KB gld_lds landing
  __shared__ __align__(16) ushort xh[2][257 * 34];   // fp16 pt-major, row 256 = 0
  __shared__ uint wls[2][257];
  __shared__ __align__(16) ushort list[2][16][64];
  __shared__ int lcnt[2][16];
  __shared__ float dn[16][2];

  const int t = threadIdx.x;
  const int wv = t >> 6;
  const int l = t & 63;
  const int c16 = l & 15;
  const bool lane16 = (l & 15) == 0;
  const int G = gridDim.x;

  f32x4 z4 = {0.f, 0.f, 0.f, 0.f};
  f32x4 a0_00=z4, a0_01=z4, a0_11=z4, a0_20=z4, a0_21=z4;
  f32x4 b0_00=z4, b0_01=z4, b0_11=z4, b0_20=z4, b0_21=z4;
  f32x4 a1_00=z4, a1_01=z4, a1_11=z4, a1_20=z4, a1_21=z4;
  f32x4 b1_00=z4, b1_01=z4, b1_11=z4, b1_20=z4, b1_21=z4;

  float wr0 = 0.f, wr1 = 0.f; int zr = 0;

  auto STAGEX = [&](int ch) {
#pragma unroll
    for (int q = 0; q < 4; ++q) {
      int gi = ch * CHUNK + wv * 32 + q * 8 + (l >> 3);
      if (gi > n - 1) gi = n - 1;
      gld_lds16(X + (size_t)gi * 32 + ((l & 7) << 2), &xf32[(wv * 32 + q * 8) * 32]);
    }
  };
  auto LOADWZ = [&](int ch) {
    if (t < CHUNK) {
      int gi = ch * CHUNK + t;
      if (gi < n) {
        float2 w2 = *(const float2*)(wpairf + (size_t)gi * 2);
        wr0 = w2.x; wr1 = w2.y; zr = zb[gi];
      } else { wr0 = 0.f; wr1 = 0.f; zr = 0; }
    }
  };
  auto CVT = [&](int nb) {
    const int p = t >> 1, hh = t & 1;
    const float4* s4 = (const float4*)(xf32 + p * 32 + hh * 16);
    uint* dst = (uint*)&xh[nb][p * 34 + hh * 16];
#pragma unroll
    for (int i = 0; i < 4; ++i) {
      int ii = (i + p) & 3;
      float4 v = s4[ii];
      dst[2 * ii]     = pkrtz(v.x, v.y);
      dst[2 * ii + 1] = pkrtz(v.z, v.w);
    }
    if (t < CHUNK) {
      wls[nb][t] = pkrtz(sqrtf(wr0), sqrtf(wr1));
      atomicAdd(&dn[zr][0], wr0);
      atomicAdd(&dn[zr][1], wr1);
      int pos = atomicAdd(&lcnt[nb][zr], 1);
      if (pos < 64) list[nb][zr][pos] = (ushort)t;
    }
  };

  if (t < 32) ((int*)lcnt)[t] = 0;
  if (t < 32) ((float*)dn)[t] = 0.f;
  if (t < 17) {
    ((uint*)&xh[0][256 * 34])[t] = 0;
    ((uint*)&xh[1][256 * 34])[t] = 0;
  }
  if (t == 0) { wls[0][256] = 0; wls[1][256] = 0; }

  int ch = blockIdx.x;
  int b = 0;
  if (ch < nchunks) {
    STAGEX(ch); LOADWZ(ch);
    WAITVM0; WAITLGKM; BAR;
    CVT(0);
    WAITLGKM; BAR;
    if (ch + G < nchunks) { STAGEX(ch + G); LOADWZ(ch + G); }
    while (true) {
      CLUSTER_MFMA(wv * 2 + 0, a0_00,a0_01,a0_11,a0_20,a0_21,
                               b0_00,b0_01,b0_11,b0_20,b0_21)
      CLUSTER_MFMA(wv * 2 + 1, a1_00,a1_01,a1_11,a1_20,a1_21,
                               b1_00,b1_01,b1_11,b1_20,b1_21)
      int chn = ch + G;
      if (chn >= nchunks) break;
      WAITVM0; WAITLGKM; BAR;
      if (t < 16) lcnt[b][t] = 0;
      CVT(b ^ 1);
      WAITLGKM; BAR;
      if (chn + G < nchunks) { STAGEX(chn + G); LOADWZ(chn + G); }
      b ^= 1; ch = chn;
    }
  }

  STORE_MFMA((wv * 2 + 0) * 2 + 0, a0_00,a0_01,a0_11,a0_20,a0_21)
  STORE_MFMA((wv * 2 + 0) * 2 + 1, b0_00,b0_01,b0_11,b0_20,b0_21)
  STORE_MFMA((wv * 2 + 1) * 2 + 0, a1_00,a1_01,a1_11,a1_20,a1_21)
  STORE_MFMA((wv * 2 + 1) * 2 + 1, b1_00,b1_01,b1_11,b1_20,b1_21)
  if (t < 32) dnp[blockIdx.x * 32 + t] = dn[t >> 1][t & 1];
}

// Partial-reduction: m2p [NB][24576] via 192 blocks, musp via 8, dnp via 1,
// pigp [PIGRID][32] via 8 slice-blocks (PIGRID/8 rows each -> pigr8[8][32]).
__global__ __launch_bounds__(256) void reduce_k(
    const float* __restrict__ m2p, const float* __restrict__ musp,
    const float* __restrict__ dnp, const float* __restrict__ pigp,
    float* __restrict__ m2r, float* __restrict__ musr,
    float* __restrict__ dnr, float* __restrict__ pigr8, int nb)
{
  const int t = threadIdx.x;
  const int bid = blockIdx.x;

  if (bid < 200) {
    __shared__ float4 red[256];
    const float* in; float* outp; int rs, colbase;
    if (bid < 192) { in = m2p;  outp = m2r;  rs = 24576; colbase = bid * 32; }
    else           { in = musp; outp = musr; rs = 1024;  colbase = (bid - 192) * 32; }
    const int col = colbase + (t & 31);
    float4 a = make_float4(0.f, 0.f, 0.f, 0.f);
#pragma unroll 4
    for (int bb = t >> 5; bb < nb; bb += 8) {
      float4 v = *(const float4*)&in[(size_t)bb * rs + col * 4];
      a.x += v.x; a.y += v.y; a.z += v.z; a.w += v.w;
    }
    red[t] = a;
    __syncthreads();
    if (t < 32) {
      float4 s = red[t];
#pragma unroll
      for (int q = 1; q < 8; ++q) {
        float4 v = red[t + q * 32];
        s.x += v.x; s.y += v.y; s.z += v.z; s.w += v.w;
      }
      *(float4*)&outp[col * 4] = s;
    }
  } else {
    __shared__ float redf[256];
    const float* in; float* outp; int rows, row0;
    if (bid == 200) { in = dnp; outp = dnr; rows = nb; row0 = 0; }
    else {
      in = pigp; outp = pigr8 + (bid - 201) * 32;
      rows = PIGRID / 8; row0 = (bid - 201) * (PIGRID / 8);
    }
    float a = 0.f;
    const int c = t & 31;
#pragma unroll 4
    for (int bb = t >> 5; bb < rows; bb += 8) a += in[(row0 + bb) * 32 + c];
    redf[t] = a;
    __syncthreads();
    if (t < 32) {
      float s = redf[t];
#pragma unroll
      for (int q = 1; q < 8; ++q) s += redf[t + q * 32];
      outp[c] = s;
    }
  }
}

// Epilogue: reconstruct full 32x32 covs from the 3-section symmetric layout.
__global__ __launch_bounds__(256) void finalize_k(
    const float* __restrict__ pigr8, const float* __restrict__ dnr,
    const float* __restrict__ musr, const float* __restrict__ m2r,
    float* __restrict__ out, int n)
{
  const int c = blockIdx.x;
  const int t = threadIdx.x;
  __shared__ float mu[32];
  float safe = fmaxf(dnr[c], 1e-10f);
  if (t < 32) {
    float m = musr[c * 32 + t] / safe;
    mu[t] = m;
    out[32 + c * 32 + t] = m;                        // mus
  }
  if (c == 0 && t < 32) {
    float p = 0.f;
#pragma unroll
    for (int s = 0; s < 8; ++s) p += pigr8[s * 32 + t];
    out[t] = p / (float)n;                           // pi
  }
  __syncthreads();
  const int d1 = t >> 3;
  const int c0 = (t * 4) & 31;
  const float* base = m2r + c * 768;
  float vals[4];
  if (d1 < 16) {
    if (c0 < 16) {
      float4 v = *(const float4*)&base[d1 * 16 + c0];
      vals[0]=v.x; vals[1]=v.y; vals[2]=v.z; vals[3]=v.w;
    } else {
      int cc = c0 - 16;
#pragma unroll
      for (int j = 0; j < 4; ++j) vals[j] = base[512 + (cc + j) * 16 + d1];
    }
  } else {
    int dd = d1 - 16;
    if (c0 < 16) {
      float4 v = *(const float4*)&base[512 + dd * 16 + c0];
      vals[0]=v.x; vals[1]=v.y; vals[2]=v.z; vals[3]=v.w;
    } else {
      float4 v = *(const float4*)&base[256 + dd * 16 + (c0 - 16)];
      vals[0]=v.x; vals[1]=v.y; vals[2]=v.z; vals[3]=v.w;
    }
  }
  float mud1 = mu[d1];
  float4 cov;
  cov.x = vals[0] / safe - mud1 * mu[c0 + 0];
  cov.y = vals[1] / safe - mud1 * mu[c0 + 1];
  cov.z = vals[2] / safe - mud1 * mu[c0 + 2];
  cov.w = vals[3] / safe - mud1 * mu[c0 + 3];
  *(float4*)&out[32 + 1024 + c * 1024 + t * 4] = cov;  // covs
}

extern "C" void kernel_launch(void* const* d_in, const int* in_sizes, int n_in,
                              void* d_out, int out_size, void* d_ws, size_t ws_size,
                              hipStream_t stream) {
  const float* X  = (const float*)d_in[0];
  const float* r  = (const float*)d_in[1];
  const float* ri = (const float*)d_in[2];
  float* out = (float*)d_out;
  const int n = in_sizes[0] / 32;
  const int nchunks = (n + CHUNK - 1) / CHUNK;

  // ws layout: [m2p | musp | dnp | m2r | musr | dnr | pigr8 | pigp | wpair | zbuf]
  float* m2p   = (float*)d_ws;                          // NB*32*768
  float* musp  = m2p + (size_t)NB * 32 * 768;           // NB*32*32
  float* dnp   = musp + (size_t)NB * 32 * 32;           // NB*32
  float* m2r   = dnp + (size_t)NB * 32;                 // 24576
  float* musr  = m2r + 24576;                           // 1024
  float* dnr   = musr + 1024;                           // 32
  float* pigr8 = dnr + 32;                              // 8*32
  float* pigp  = pigr8 + 8 * 32;                        // PIGRID*32
  float* wpair = pigp + (size_t)PIGRID * 32;            // 2n
  unsigned char* zbuf = (unsigned char*)(wpair + 2 * (size_t)n);  // n + pad

  fused_k<<<PIGRID, 256, 0, stream>>>(r, ri, zbuf, wpair, pigp, n);
  mstep_k<<<NB, 512, 0, stream>>>(X, zbuf, wpair, m2p, musp, dnp, n, nchunks);
  reduce_k<<<209, 256, 0, stream>>>(m2p, musp, dnp, pigp, m2r, musr, dnr, pigr8, NB);
  finalize_k<<<32, 256, 0, stream>>>(pigr8, dnr, musr, m2r, out, n);
}